// Round 1
// baseline (331.490 us; speedup 1.0000x reference)
//
#include <hip/hip_runtime.h>

// Problem: single-head causal attention, FUSED (R4: 16-wave blocks).
// B=512, T=256, C=384, H=64. Inputs fp32: x[B,T,C], Wq/Wk/Wv[C,H]. Out fp32 [B,T,H].
// Scale is C^-0.5 (note: n_embed, not head_size).
#define B_ 512
#define T_ 256
#define C_ 384
#define H_ 64

typedef __attribute__((ext_vector_type(8))) short bf16x8;   // 4 VGPRs, MFMA A/B frag
typedef __attribute__((ext_vector_type(4))) float f32x4;    // MFMA C/D frag

// fp32 -> bf16 (RNE). Data is finite; no NaN handling needed.
__device__ __forceinline__ short f2bf(float f) {
    unsigned u = __float_as_uint(f);
    u += 0x7fffu + ((u >> 16) & 1u);
    return (short)(u >> 16);
}

__device__ __forceinline__ bf16x8 pack8(float4 a, float4 b) {
    bf16x8 r;
    r[0] = f2bf(a.x); r[1] = f2bf(a.y); r[2] = f2bf(a.z); r[3] = f2bf(a.w);
    r[4] = f2bf(b.x); r[5] = f2bf(b.y); r[6] = f2bf(b.z); r[7] = f2bf(b.w);
    return r;
}

// ---------------------------------------------------------------------------
// Kernel 0: pack Wq|Wk|Wv (fp32, [C][H] each) into bf16 MFMA B-fragment order.
// Combined N = 192 (q:0-63, k:64-127, v:128-191). K = C = 384.
// Packed index p = ((ks*12 + ct)*64 + lane)*8 + j,
//   where n = ct*16 + (lane&15), k = ks*32 + (lane>>4)*8 + j.
// ---------------------------------------------------------------------------
__global__ void pack_w_kernel(const float* __restrict__ Wq, const float* __restrict__ Wk,
                              const float* __restrict__ Wv, short* __restrict__ wp) {
    int p = blockIdx.x * 256 + threadIdx.x;
    if (p >= 12 * 12 * 512) return;           // 73728 shorts total
    int j    = p & 7;
    int lane = (p >> 3) & 63;
    int pc   = p >> 9;                         // ks*12 + ct
    int ct = pc % 12, ks = pc / 12;
    int n  = ct * 16 + (lane & 15);
    int kk = ks * 32 + (lane >> 4) * 8 + j;
    const float* src = (n < 64) ? Wq : ((n < 128) ? Wk : Wv);
    wp[p] = f2bf(src[kk * 64 + (n & 63)]);
}

// ---------------------------------------------------------------------------
// Kernel 1 (FUSED): one block of 1024 thr (16 waves) per batch.
// R4 change vs R3: 8->16 waves/block. Per-wave output frags 24->12, so the
// phase-1 accumulator drops from 96 to 48 AGPRs. R3's 96-AGPR acc + 80 arch
// VGPRs = ~176 regs/wave -> 2 waves/SIMD (the measured 21% occupancy) ->
// nothing hides HBM latency. Now total regs <=128 (__launch_bounds__(1024,4))
// -> 4 waves/SIMD, 16 waves/CU, plus register room for depth-2 x prefetch.
//
// Wave w owns row-group rg = (w&12) | ((w&3)^(w>>2)) in BOTH phases (Q stays
// in registers). Bijection; per-SIMD (w&3) causal work is balanced (34 tiles).
//
// LDS: Ks 32K + Vs 32K + Pb 20K = 86016 B -> 1 block/CU (16 waves = 50% occ).
// ---------------------------------------------------------------------------
__global__ __launch_bounds__(1024, 4) void fused_kernel(
    const float* __restrict__ x, const short* __restrict__ wp,
    float* __restrict__ out) {
    // Frag layout in Ks: frag(ts,kk) at (ts*2+kk)*512; element (t,h):
    //   lane' = (t&15) + 16*((h&31)>>3), j = h&7.  (t = key row, h = head dim)
    // Frag layout in Vs: frag(c,ht) at (c*4+ht)*512; element (t,h):
    //   lane' = (h&15) + 16*((t>>3)&3), j = t&7.   (k-dim = t, n-dim = h)
    __shared__ short Ks[32 * 512];            // 32768 B
    __shared__ short Vs[32 * 512];            // 32768 B
    __shared__ short Pb[16][16 * 40];         // 20480 B per-wave scratch

    const int b = blockIdx.x;
    const int tid = threadIdx.x;
    const int w = tid >> 6, lane = tid & 63;
    const int cl = lane & 15, quad = lane >> 4;

    // Row-group (= phase-1 row-tile) for this wave; SIMD-balanced bijection.
    const int rg = (w & 12) | ((w & 3) ^ (w >> 2));
    const int base = rg << 4;

    // ---------------- Phase 1: QKV projection for this wave's 16 rows -------
    const float* xb = x + (long)b * (T_ * C_);
    // Lane reads row (base+cl), k-slice quad*8 + [0,8) each ks step.
    const float4* xr = (const float4*)(xb + (long)(base + cl) * C_) + quad * 2;

    f32x4 acc[12];
    #pragma unroll
    for (int ct = 0; ct < 12; ct++) {
        f32x4 z = {0.f, 0.f, 0.f, 0.f};
        acc[ct] = z;
    }

    // Depth-2 software pipeline on the x loads (rotating 3-stage buffer,
    // statically indexed under full unroll). Keeps >=2KB/wave in flight.
    float4 xa[3][2];
    xa[0][0] = xr[0]; xa[0][1] = xr[1];       // ks=0
    xa[1][0] = xr[8]; xa[1][1] = xr[9];       // ks=1 (stride 32 floats = 8 f4)
    const short* wl = wp + lane * 8;
    #pragma unroll
    for (int ks = 0; ks < 12; ks++) {
        if (ks < 10) {                        // prefetch ks+2
            xa[(ks + 2) % 3][0] = xr[(ks + 2) * 8];
            xa[(ks + 2) % 3][1] = xr[(ks + 2) * 8 + 1];
        }
        bf16x8 a = pack8(xa[ks % 3][0], xa[ks % 3][1]);
        const short* wk = wl + ks * 6144;     // ks-chunk = 12 frags x 512 shorts
        #pragma unroll
        for (int ct = 0; ct < 12; ct++) {
            bf16x8 bf = *(const bf16x8*)(wk + ct * 512);
            acc[ct] = __builtin_amdgcn_mfma_f32_16x16x32_bf16(a, bf, acc[ct], 0, 0, 0);
        }
    }

    // ---------------- Epilogue: K,V -> LDS; Q -> A-frags in registers -------
    // C/D layout: acc[ct][r] is element (t = base + quad*4 + r, n = ct*16+cl).
    const int tb = base + quad * 4;
    // K: ct 4..7, h = (ct-4)*16 + cl.
    #pragma unroll
    for (int ct = 4; ct < 8; ct++) {
        const int h = (ct - 4) * 16 + cl;
        const int kk = h >> 5, hq = (h & 31) >> 3, j = h & 7;
        #pragma unroll
        for (int r = 0; r < 4; r++) {
            const int t = tb + r;
            Ks[((t >> 4) * 2 + kk) * 512 + ((t & 15) + 16 * hq) * 8 + j] =
                f2bf(acc[ct][r]);
        }
    }
    // V: ct 8..11, h = (ct-8)*16 + cl, ht = ct-8.
    #pragma unroll
    for (int ct = 8; ct < 12; ct++) {
        const int ht = ct - 8;
        #pragma unroll
        for (int r = 0; r < 4; r++) {
            const int t = tb + r;
            Vs[((t >> 5) * 4 + ht) * 512 + (cl + 16 * ((t >> 3) & 3)) * 8 + (t & 7)] =
                f2bf(acc[ct][r]);
        }
    }

    // Q: ct 0..3 (h = ct*16+cl). Convert C-layout -> A-frags via per-wave Pb.
    short* pb = Pb[w];
    bf16x8 qf[2];
    #pragma unroll
    for (int kk = 0; kk < 2; kk++) {
        #pragma unroll
        for (int cth = 0; cth < 2; cth++) {
            const int ct = kk * 2 + cth;
            #pragma unroll
            for (int r = 0; r < 4; r++)
                pb[(quad * 4 + r) * 40 + cth * 16 + cl] = f2bf(acc[ct][r]);
        }
        __builtin_amdgcn_wave_barrier();
        qf[kk] = *(const bf16x8*)(pb + cl * 40 + quad * 8);  // m=cl, k=quad*8+j
        __builtin_amdgcn_wave_barrier();
    }

    __syncthreads();   // Ks/Vs written by all waves before any wave reads

    // ---------------- Phase 2: causal attention ----------------------------
    // scale = 384^-0.5, with log2(e) folded in (exp via exp2).
    const float scale2 = 0.05103103630798287f * 1.4426950408889634f;

    const bf16x8 qf0 = qf[0];
    const bf16x8 qf1 = qf[1];

    // S = Q K^T, tiles st <= rg (wave-uniform guards).
    f32x4 sacc[16];
    #pragma unroll
    for (int st = 0; st < 16; st++) {
        if (st > rg) continue;
        bf16x8 k0 = *(const bf16x8*)(Ks + (st * 2 + 0) * 512 + lane * 8);
        bf16x8 k1 = *(const bf16x8*)(Ks + (st * 2 + 1) * 512 + lane * 8);
        f32x4 z = {0.f, 0.f, 0.f, 0.f};
        f32x4 t = __builtin_amdgcn_mfma_f32_16x16x32_bf16(qf0, k0, z, 0, 0, 0);
        t = __builtin_amdgcn_mfma_f32_16x16x32_bf16(qf1, k1, t, 0, 0, 0);
        sacc[st] = t;
    }

    // Scale (pre-multiplied by log2e), causal mask, row max.
    float m4[4] = {-3e38f, -3e38f, -3e38f, -3e38f};
    #pragma unroll
    for (int st = 0; st < 16; st++) {
        if (st > rg) continue;
        #pragma unroll
        for (int r = 0; r < 4; r++) {
            float sv = sacc[st][r] * scale2;
            if (st * 16 + cl > base + quad * 4 + r) sv = -1e30f;
            sacc[st][r] = sv;
            m4[r] = fmaxf(m4[r], sv);
        }
    }
    #pragma unroll
    for (int d = 1; d < 16; d <<= 1)
        #pragma unroll
        for (int r = 0; r < 4; r++)
            m4[r] = fmaxf(m4[r], __shfl_xor(m4[r], d));

    // exp + row sum (masked entries -> 0 exactly).
    float l4[4] = {0.f, 0.f, 0.f, 0.f};
    #pragma unroll
    for (int st = 0; st < 16; st++) {
        if (st > rg) continue;
        #pragma unroll
        for (int r = 0; r < 4; r++) {
            float pv = exp2f(sacc[st][r] - m4[r]);
            sacc[st][r] = pv;
            l4[r] += pv;
        }
    }
    #pragma unroll
    for (int d = 1; d < 16; d <<= 1)
        #pragma unroll
        for (int r = 0; r < 4; r++)
            l4[r] += __shfl_xor(l4[r], d);

    // O = P V over s-chunks of 32 (chunks c <= rg/2). P via Pb round-trip.
    f32x4 oacc[4];
    #pragma unroll
    for (int ht = 0; ht < 4; ht++) {
        f32x4 z = {0.f, 0.f, 0.f, 0.f};
        oacc[ht] = z;
    }
    #pragma unroll
    for (int c = 0; c < 8; c++) {
        if (c > (rg >> 1)) continue;
        #pragma unroll
        for (int half = 0; half < 2; half++) {
            const int st = c * 2 + half;
            #pragma unroll
            for (int r = 0; r < 4; r++) {
                short pv = (st <= rg) ? f2bf(sacc[st][r]) : (short)0;
                pb[(quad * 4 + r) * 40 + half * 16 + cl] = pv;
            }
        }
        __builtin_amdgcn_wave_barrier();
        const bf16x8 pa = *(const bf16x8*)(pb + cl * 40 + quad * 8);
        #pragma unroll
        for (int ht = 0; ht < 4; ht++) {
            const bf16x8 vf = *(const bf16x8*)(Vs + (c * 4 + ht) * 512 + lane * 8);
            oacc[ht] = __builtin_amdgcn_mfma_f32_16x16x32_bf16(pa, vf, oacc[ht], 0, 0, 0);
        }
        __builtin_amdgcn_wave_barrier();
    }

    // Out: O row r is in the same lanes as l4[r].
    #pragma unroll
    for (int r = 0; r < 4; r++) {
        const float inv = 1.0f / l4[r];
        float* op = out + (long)(b * T_ + base + quad * 4 + r) * H_ + cl;
        #pragma unroll
        for (int ht = 0; ht < 4; ht++)
            op[ht * 16] = oacc[ht][r] * inv;
    }
}

// ---------------------------------------------------------------------------
extern "C" void kernel_launch(void* const* d_in, const int* in_sizes, int n_in,
                              void* d_out, int out_size, void* d_ws, size_t ws_size,
                              hipStream_t stream) {
    const float* x  = (const float*)d_in[0];
    const float* Wq = (const float*)d_in[1];
    const float* Wk = (const float*)d_in[2];
    const float* Wv = (const float*)d_in[3];
    float* out = (float*)d_out;

    short* wp = (short*)d_ws;   // packed W: 73728 shorts = 147 KB

    pack_w_kernel<<<288, 256, 0, stream>>>(Wq, Wk, Wv, wp);
    fused_kernel<<<B_, 1024, 0, stream>>>(x, wp, out);
}

// Round 3
// 311.967 us; speedup vs baseline: 1.0626x; 1.0626x over previous
//
#include <hip/hip_runtime.h>

// Problem: single-head causal attention, FUSED (R6 = R5 + swizzle-read fix).
// B=512, T=256, C=384, H=64. Inputs fp32: x[B,T,C], Wq/Wk/Wv[C,H]. Out fp32 [B,T,H].
// Scale is C^-0.5 (note: n_embed, not head_size).
//
// R5 post-mortem: A-frag read used '+ kl*64' where the granule swizzle algebra
// requires '^ kl*64' (G' = (kl*4+quad) ^ (cl&7); '+' carries into the row bits
// when cl&4). Fixed; all else identical to R5.
#define B_ 512
#define T_ 256
#define C_ 384
#define H_ 64

typedef __attribute__((ext_vector_type(8))) short bf16x8;   // 4 VGPRs, MFMA A/B frag
typedef __attribute__((ext_vector_type(4))) float f32x4;    // MFMA C/D frag

// fp32 -> bf16 (RNE). Data is finite; no NaN handling needed.
__device__ __forceinline__ short f2bf(float f) {
    unsigned u = __float_as_uint(f);
    u += 0x7fffu + ((u >> 16) & 1u);
    return (short)(u >> 16);
}

// pack 4 fp32 -> 4 bf16 in one 8-B value (for ds_write_b64).
__device__ __forceinline__ unsigned long long pack4(float4 a) {
    return  (unsigned long long)(unsigned short)f2bf(a.x)
         | ((unsigned long long)(unsigned short)f2bf(a.y) << 16)
         | ((unsigned long long)(unsigned short)f2bf(a.z) << 32)
         | ((unsigned long long)(unsigned short)f2bf(a.w) << 48);
}

// ---------------------------------------------------------------------------
// Kernel 0: pack Wq|Wk|Wv (fp32, [C][H] each) into bf16 MFMA B-fragment order.
// Combined N = 192 (q:0-63, k:64-127, v:128-191). K = C = 384.
// Packed index p = ((ks*12 + ct)*64 + lane)*8 + j,
//   where n = ct*16 + (lane&15), k = ks*32 + (lane>>4)*8 + j.
// ---------------------------------------------------------------------------
__global__ void pack_w_kernel(const float* __restrict__ Wq, const float* __restrict__ Wk,
                              const float* __restrict__ Wv, short* __restrict__ wp) {
    int p = blockIdx.x * 256 + threadIdx.x;
    if (p >= 12 * 12 * 512) return;           // 73728 shorts total
    int j    = p & 7;
    int lane = (p >> 3) & 63;
    int pc   = p >> 9;                         // ks*12 + ct
    int ct = pc % 12, ks = pc / 12;
    int n  = ct * 16 + (lane & 15);
    int kk = ks * 32 + (lane >> 4) * 8 + j;
    const float* src = (n < 64) ? Wq : ((n < 128) ? Wk : Wv);
    wp[p] = f2bf(src[kk * 64 + (n & 63)]);
}

// ---------------------------------------------------------------------------
// Kernel 1 (FUSED): one block of 1024 thr (16 waves) per batch.
//
// Phase 1 (QKV GEMM, K-chunked): 6 chunks of 64 K-cols. Per chunk:
//   - stage: each wave loads its 16 rows x 64 cols fp32 as 4 dwordx4 instrs
//     (4 rows x 256 B contiguous each), converts to bf16, ds_write_b64 into a
//     double-buffered swizzled LDS tile Xs[256 rows][8 granules of 16B], with
//     granule swizzle G' = G ^ (row&7)  (conflict-free write AND read).
//   - compute: wave w owns rts {(w&3)*4+[0,4)}, cts {(w>>2)*3+[0,3)}:
//     per ks: 4 A-frags from Xs (ds_read_b128), 3 B-frags from wp (L2),
//     12 MFMA. B loads issued before stage loads so B vmcnt waits don't drain
//     the in-flight stage (in-order vmcnt retirement).
// Epilogue: acc -> Qs/Ks/Vs in LDS (frag layouts), aliasing the dead Xs.
// Phase 2: identical to R4, except Q read from Qs (1 ds_read_b128 per frag).
//
// LDS: phase1 Xs dbuf 64K; phase2 Qs 32K + Ks 32K + Vs 32K + Pb 20K = 116K.
// Static = 116 KB (union) -> 1 block/CU, 16 waves (4/SIMD).
// ---------------------------------------------------------------------------
__global__ __launch_bounds__(1024, 4) void fused_kernel(
    const float* __restrict__ x, const short* __restrict__ wp,
    float* __restrict__ out) {
    __shared__ char lds_raw[118784];
    short* Qs = (short*)lds_raw;                 // phase2: 32768 B (aliases Xs buf0)
    short* Ks = (short*)(lds_raw + 32768);       // 32768 B (aliases Xs buf1)
    short* Vs = (short*)(lds_raw + 65536);       // 32768 B
    short* Pb = (short*)(lds_raw + 98304);       // 16 x 640 shorts = 20480 B

    const int b = blockIdx.x;
    const int tid = threadIdx.x;
    const int w = tid >> 6, lane = tid & 63;
    const int cl = lane & 15, quad = lane >> 4;

    const float* xb = x + (long)b * (T_ * C_);
    const float4* xb4 = (const float4*)xb;       // 96 float4 per row

    // ----- staging address precompute (per lane) ---------------------------
    // instr i (0..3): row = w*16 + i*4 + quad, f4-col cg = cl (0..15).
    // global f4 idx = row*96 + c*16 + cl.
    // LDS byte addr = buf + row*128 + ((G ^ (row&7))<<4) + sub*8,
    //   G = cl>>1, sub = lane&1, row&7 = quad (i even) / quad^4 (i odd).
    const int srow = w * 16 + quad;              // row for i=0; +4 per i
    const unsigned st_even = (unsigned)(w * 2048 + quad * 128)
                           + (((unsigned)(cl >> 1) ^ (unsigned)quad) << 4)
                           + (unsigned)(lane & 1) * 8;
    const unsigned st_odd = st_even ^ 64u;       // row&7 ^= 4 -> granule bit2 flips

    // ----- A-frag read precompute ------------------------------------------
    const int rtb = (w & 3) * 4;                 // rt base (4 row-tiles)
    const int ctb = (w >> 2) * 3;                // ct base (3 col-tiles)
    // Frag (rt=rtb+i, kl): row = rt*16+cl, G = kl*4+quad, G' = G ^ (cl&7).
    // addr = (rt*16+cl)*128 + (G'<<4) = (abase + i*2048) ^ (kl*64)
    //   since bit2 of (quad ^ (cl&7)) flips under the kl term (quad<4). [R5 bug: was '+']
    const unsigned abase = (unsigned)((rtb * 16 + cl) * 128)
                         + (((unsigned)quad ^ (unsigned)(cl & 7)) << 4);

    const short* wlB = wp + ctb * 512 + lane * 8;   // + ks*6144 + j*512

    f32x4 acc[4][3];
    #pragma unroll
    for (int i = 0; i < 4; i++)
        #pragma unroll
        for (int j = 0; j < 3; j++) {
            f32x4 z = {0.f, 0.f, 0.f, 0.f};
            acc[i][j] = z;
        }

    // ----- prologue: stage chunk 0 into buf 0 ------------------------------
    {
        float4 sv[4];
        #pragma unroll
        for (int i = 0; i < 4; i++)
            sv[i] = xb4[(srow + i * 4) * 96 + cl];
        #pragma unroll
        for (int i = 0; i < 4; i++) {
            unsigned a = ((i & 1) ? st_odd : st_even) + (unsigned)i * 512u;
            *(unsigned long long*)(lds_raw + a) = pack4(sv[i]);
        }
    }
    __syncthreads();

    // ----- main K-chunk loop ----------------------------------------------
    for (int c = 0; c < 6; ++c) {
        // B-frags for both ks of this chunk (issued FIRST: their vmcnt waits
        // must not force the stage loads below to drain).
        bf16x8 bfr[2][3];
        #pragma unroll
        for (int kl = 0; kl < 2; kl++) {
            const short* wk = wlB + (c * 2 + kl) * 6144;
            #pragma unroll
            for (int j = 0; j < 3; j++)
                bfr[kl][j] = *(const bf16x8*)(wk + j * 512);
        }

        // stage loads for chunk c+1 (in flight across the compute below).
        float4 sv[4];
        if (c < 5) {
            #pragma unroll
            for (int i = 0; i < 4; i++)
                sv[i] = xb4[(srow + i * 4) * 96 + (c + 1) * 16 + cl];
        }

        // compute: 2 ks-steps from Xs[buf c&1].
        const char* buf = lds_raw + (c & 1) * 32768;
        #pragma unroll
        for (int kl = 0; kl < 2; kl++) {
            bf16x8 af[4];
            #pragma unroll
            for (int i = 0; i < 4; i++)
                af[i] = *(const bf16x8*)(buf +
                    ((abase + (unsigned)i * 2048u) ^ (kl ? 64u : 0u)));
            #pragma unroll
            for (int i = 0; i < 4; i++)
                #pragma unroll
                for (int j = 0; j < 3; j++)
                    acc[i][j] = __builtin_amdgcn_mfma_f32_16x16x32_bf16(
                        af[i], bfr[kl][j], acc[i][j], 0, 0, 0);
        }

        // write staged chunk c+1 into buf (c+1)&1.
        if (c < 5) {
            char* nbuf = lds_raw + ((c + 1) & 1) * 32768;
            #pragma unroll
            for (int i = 0; i < 4; i++) {
                unsigned a = ((i & 1) ? st_odd : st_even) + (unsigned)i * 512u;
                *(unsigned long long*)(nbuf + a) = pack4(sv[i]);
            }
        }
        __syncthreads();
    }

    // ---------------- Epilogue: acc -> Qs / Ks / Vs (over dead Xs) ---------
    // C/D layout: acc[i][j][r] is element (t = (rtb+i)*16 + quad*4 + r,
    //   n = (ctb+j)*16 + cl).  ct<4 -> Q, ct<8 -> K, else V (wave-uniform).
    #pragma unroll
    for (int j = 0; j < 3; j++) {
        const int ct = ctb + j;
        if (ct < 4) {           // Q: h = ct*16 + cl
            const int h = ct * 16 + cl;
            const int kk = h >> 5, hq = (h >> 3) & 3, jj = h & 7;
            #pragma unroll
            for (int i = 0; i < 4; i++)
                #pragma unroll
                for (int r = 0; r < 4; r++)
                    Qs[((rtb + i) * 2 + kk) * 512 + ((quad * 4 + r) + 16 * hq) * 8 + jj] =
                        f2bf(acc[i][j][r]);
        } else if (ct < 8) {    // K: h = (ct-4)*16 + cl
            const int h = (ct - 4) * 16 + cl;
            const int kk = h >> 5, hq = (h >> 3) & 3, jj = h & 7;
            #pragma unroll
            for (int i = 0; i < 4; i++)
                #pragma unroll
                for (int r = 0; r < 4; r++)
                    Ks[((rtb + i) * 2 + kk) * 512 + ((quad * 4 + r) + 16 * hq) * 8 + jj] =
                        f2bf(acc[i][j][r]);
        } else {                // V: h = (ct-8)*16 + cl, ht = ct-8
            const int ht = ct - 8;
            #pragma unroll
            for (int i = 0; i < 4; i++)
                #pragma unroll
                for (int r = 0; r < 4; r++) {
                    const int t = (rtb + i) * 16 + quad * 4 + r;
                    Vs[((t >> 5) * 4 + ht) * 512 + (cl + 16 * ((t >> 3) & 3)) * 8 + (t & 7)] =
                        f2bf(acc[i][j][r]);
                }
        }
    }

    __syncthreads();   // Qs/Ks/Vs complete before any wave reads

    // ---------------- Phase 2: causal attention ----------------------------
    // scale = 384^-0.5, with log2(e) folded in (exp via exp2).
    const float scale2 = 0.05103103630798287f * 1.4426950408889634f;

    // Row-group for this wave; SIMD-balanced bijection.
    const int rg = (w & 12) | ((w & 3) ^ (w >> 2));
    const int base = rg << 4;
    short* pb = Pb + w * 640;

    const bf16x8 qf0 = *(const bf16x8*)(Qs + (rg * 2 + 0) * 512 + lane * 8);
    const bf16x8 qf1 = *(const bf16x8*)(Qs + (rg * 2 + 1) * 512 + lane * 8);

    // S = Q K^T, tiles st <= rg (wave-uniform guards).
    f32x4 sacc[16];
    #pragma unroll
    for (int st = 0; st < 16; st++) {
        if (st > rg) continue;
        bf16x8 k0 = *(const bf16x8*)(Ks + (st * 2 + 0) * 512 + lane * 8);
        bf16x8 k1 = *(const bf16x8*)(Ks + (st * 2 + 1) * 512 + lane * 8);
        f32x4 z = {0.f, 0.f, 0.f, 0.f};
        f32x4 t = __builtin_amdgcn_mfma_f32_16x16x32_bf16(qf0, k0, z, 0, 0, 0);
        t = __builtin_amdgcn_mfma_f32_16x16x32_bf16(qf1, k1, t, 0, 0, 0);
        sacc[st] = t;
    }

    // Scale (pre-multiplied by log2e), causal mask, row max.
    float m4[4] = {-3e38f, -3e38f, -3e38f, -3e38f};
    #pragma unroll
    for (int st = 0; st < 16; st++) {
        if (st > rg) continue;
        #pragma unroll
        for (int r = 0; r < 4; r++) {
            float sv = sacc[st][r] * scale2;
            if (st * 16 + cl > base + quad * 4 + r) sv = -1e30f;
            sacc[st][r] = sv;
            m4[r] = fmaxf(m4[r], sv);
        }
    }
    #pragma unroll
    for (int d = 1; d < 16; d <<= 1)
        #pragma unroll
        for (int r = 0; r < 4; r++)
            m4[r] = fmaxf(m4[r], __shfl_xor(m4[r], d));

    // exp + row sum (masked entries -> 0 exactly).
    float l4[4] = {0.f, 0.f, 0.f, 0.f};
    #pragma unroll
    for (int st = 0; st < 16; st++) {
        if (st > rg) continue;
        #pragma unroll
        for (int r = 0; r < 4; r++) {
            float pv = exp2f(sacc[st][r] - m4[r]);
            sacc[st][r] = pv;
            l4[r] += pv;
        }
    }
    #pragma unroll
    for (int d = 1; d < 16; d <<= 1)
        #pragma unroll
        for (int r = 0; r < 4; r++)
            l4[r] += __shfl_xor(l4[r], d);

    // O = P V over s-chunks of 32 (chunks cc <= rg/2). P via Pb round-trip.
    f32x4 oacc[4];
    #pragma unroll
    for (int ht = 0; ht < 4; ht++) {
        f32x4 z = {0.f, 0.f, 0.f, 0.f};
        oacc[ht] = z;
    }
    #pragma unroll
    for (int cc = 0; cc < 8; cc++) {
        if (cc > (rg >> 1)) continue;
        #pragma unroll
        for (int half = 0; half < 2; half++) {
            const int st = cc * 2 + half;
            #pragma unroll
            for (int r = 0; r < 4; r++) {
                short pv = (st <= rg) ? f2bf(sacc[st][r]) : (short)0;
                pb[(quad * 4 + r) * 40 + half * 16 + cl] = pv;
            }
        }
        __builtin_amdgcn_wave_barrier();
        const bf16x8 pa = *(const bf16x8*)(pb + cl * 40 + quad * 8);
        #pragma unroll
        for (int ht = 0; ht < 4; ht++) {
            const bf16x8 vf = *(const bf16x8*)(Vs + (cc * 4 + ht) * 512 + lane * 8);
            oacc[ht] = __builtin_amdgcn_mfma_f32_16x16x32_bf16(pa, vf, oacc[ht], 0, 0, 0);
        }
        __builtin_amdgcn_wave_barrier();
    }

    // Out: O row r is in the same lanes as l4[r].
    #pragma unroll
    for (int r = 0; r < 4; r++) {
        const float inv = 1.0f / l4[r];
        float* op = out + (long)(b * T_ + base + quad * 4 + r) * H_ + cl;
        #pragma unroll
        for (int ht = 0; ht < 4; ht++)
            op[ht * 16] = oacc[ht][r] * inv;
    }
}

// ---------------------------------------------------------------------------
extern "C" void kernel_launch(void* const* d_in, const int* in_sizes, int n_in,
                              void* d_out, int out_size, void* d_ws, size_t ws_size,
                              hipStream_t stream) {
    const float* x  = (const float*)d_in[0];
    const float* Wq = (const float*)d_in[1];
    const float* Wk = (const float*)d_in[2];
    const float* Wv = (const float*)d_in[3];
    float* out = (float*)d_out;

    short* wp = (short*)d_ws;   // packed W: 73728 shorts = 147 KB

    pack_w_kernel<<<288, 256, 0, stream>>>(Wq, Wk, Wv, wp);
    fused_kernel<<<B_, 1024, 0, stream>>>(x, wp, out);
}